// Round 9
// baseline (249.525 us; speedup 1.0000x reference)
//
#include <hip/hip_runtime.h>
#include <stdint.h>

typedef uint32_t u32;
typedef unsigned long long u64;
typedef float f4 __attribute__((ext_vector_type(4)));

#define WGATES 32768
#define BATCH  128
#define LAYERS 32
#define NROUND (LAYERS / 2)             // 16 sync rounds, 2 layers each
#define NTYPES 16
#define NC 128                          // compute-role blocks (1 gate/thread)
#define WPL (WGATES * 4)                // packed words per layer = 131072
#define F4L (WGATES * BATCH / 4)        // float4 per layer block = 1048576

// ws layout (u32 units):
//   [0,16)              tt truth tables
//   [1024, ...)         sub-counters: round r at 1024+r*1024, j=0..15 at +j*16
//   [34816, ...)        lvl2 counters: round r at 34816+r*16
//   [35840, ...)        done flags: round r at 35840+r*1024, j=0..63 at +j*16
//   [69632, +33*WPL)    packed states S_0..S_32 (each address written once)
#define WS_SUB_OFF    1024
#define WS_LVL2_OFF   34816
#define WS_DONE_OFF   35840
#define WS_S_OFF      69632
#define WS_NEED_BYTES ((size_t)(WS_S_OFF + 33 * WPL) * 4)

// Agent-scope (sc1) accesses: ONLY for sync + state release. Data reads use
// normal cached loads (each S_l address is written once per launch; consumers
// first-touch only after the producer's sc1 store reached the coherence
// point; replay staleness is benign because replays recompute identical S).
__device__ __forceinline__ u32 agent_load(const u32* p) {
    return __hip_atomic_load(p, __ATOMIC_RELAXED, __HIP_MEMORY_SCOPE_AGENT);
}
__device__ __forceinline__ void agent_store(u32* p, u32 v) {
    __hip_atomic_store(p, v, __ATOMIC_RELAXED, __HIP_MEMORY_SCOPE_AGENT);
}
__device__ __forceinline__ void agent_store64(u64* p, u64 v) {
    __hip_atomic_store(p, v, __ATOMIC_RELAXED, __HIP_MEMORY_SCOPE_AGENT);
}
__device__ __forceinline__ u32 agent_add(u32* p, u32 v) {
    return __hip_atomic_fetch_add(p, v, __ATOMIC_RELAXED, __HIP_MEMORY_SCOPE_AGENT);
}

__device__ __forceinline__ void lut_masks(u32 tt, u32 m[16]) {
    #pragma unroll
    for (int j = 0; j < 16; ++j)
        m[j] = (u32)(((int)(tt << (31 - j))) >> 31);
}
__device__ __forceinline__ u32 lut_mux(const u32 m[16], u32 a, u32 b, u32 c, u32 d) {
    u32 na = ~a, nb = ~b, nc = ~c, nd = ~d;
    u32 v0 = (m[1]&a)|(m[0]&na),  v1 = (m[3]&a)|(m[2]&na);
    u32 v2 = (m[5]&a)|(m[4]&na),  v3 = (m[7]&a)|(m[6]&na);
    u32 v4 = (m[9]&a)|(m[8]&na),  v5 = (m[11]&a)|(m[10]&na);
    u32 v6 = (m[13]&a)|(m[12]&na),v7 = (m[15]&a)|(m[14]&na);
    u32 u0 = (b&v1)|(nb&v0), u1 = (b&v3)|(nb&v2);
    u32 u2 = (b&v5)|(nb&v4), u3 = (b&v7)|(nb&v6);
    u32 w0 = (c&u1)|(nc&u0), w1 = (c&u3)|(nc&u2);
    return (d&w1)|(nd&w0);
}

// Single-lane, single-line poll per round.
__device__ __forceinline__ void wait_done(const u32* ws, int r, int line,
                                          int tid, int slp) {
    if (tid == 0) {
        const u32* p = ws + WS_DONE_OFF + (size_t)r * 1024 + line * 16;
        if (slp == 1) { while (agent_load(p) == 0) __builtin_amdgcn_s_sleep(1); }
        else         { while (agent_load(p) == 0) __builtin_amdgcn_s_sleep(8); }
    }
    __syncthreads();
    asm volatile("" ::: "memory");
}

// ---------------------------------------------------------------------------
// pack_main: tt tables -> ws, zero all sync state, pack h0 -> S_0.
// ---------------------------------------------------------------------------
__global__ void pack_main(const float* __restrict__ feature,
                          const float* __restrict__ activation,
                          u32* __restrict__ ws) {
    int t = blockIdx.x * 256 + threadIdx.x;
    if (blockIdx.x == 0 && threadIdx.x < NTYPES) {
        u32 tt = 0;
        #pragma unroll
        for (int m = 0; m < 16; ++m)
            tt |= (activation[threadIdx.x * 16 + m] != 0.0f ? 1u : 0u) << m;
        ws[threadIdx.x] = tt;
    }
    int z = (int)blockIdx.x - 1;
    if (z >= 0 && z < 268)             // zero [1024, 69632): sub+lvl2+done
        ws[1024 + z * 256 + threadIdx.x] = 0;
    float v = feature[t];
    u64 m = __ballot(v != 0.0f);
    if ((t & 63) == 0)
        ((u64*)(ws + WS_S_OFF))[t >> 6] = m;
}

// ---------------------------------------------------------------------------
// Persistent producer-consumer kernel, TWO LAYERS PER SYNC ROUND.
// Compute thread (gate g, round r): gather own odd-layer sources (4) plus the
// 2-level cone of its even-layer gate (4 source gates x 4 = 16) from
// S_{2r-2}; evaluate 4 transient source gates + own odd + own even; store
// S_{2r-1}[g] and S_{2r}[g]. Index/descriptor loads (static) issue BEFORE the
// round gate so their latency hides under the wait.
// Blocks [NC,NC+NU): stream-unpack, woken once per round for 2 layers.
// ---------------------------------------------------------------------------
__global__ __launch_bounds__(256) void coop_kernel(
        const int* __restrict__ src_idx,
        const int* __restrict__ cell_type,
        u32* __restrict__ ws,
        float* __restrict__ out,
        int NU)
{
    u32* Sb = ws + WS_S_OFF;
    int tid = threadIdx.x;
    __shared__ u32 stt[NTYPES];
    if (tid < NTYPES) stt[tid] = ws[tid];
    __syncthreads();

    if ((int)blockIdx.x < NC) {
        // ---------------- compute role: gate-per-thread, 2-layer cone ------
        int g = blockIdx.x * 256 + tid;     // gate id in [0, WGATES)
        int sub = blockIdx.x & 15;          // 16 sub-counters x 8 blocks
        for (int r = 1; r <= NROUND; ++r) {
            const int l1 = 2 * r - 1, l2 = 2 * r;
            const int4* S1 = (const int4*)(src_idx + (size_t)(l1 - 1) * WGATES * 4);
            const int4* S2 = (const int4*)(src_idx + (size_t)(l2 - 1) * WGATES * 4);
            const int*  C1 = cell_type + (size_t)(l1 - 1) * WGATES;
            const int*  C2 = cell_type + (size_t)(l2 - 1) * WGATES;
            // Static index/descriptor loads (resolve during the wait).
            int4 i1 = S1[g];
            int4 i2 = S2[g];
            u32 c1 = stt[C1[g]];
            u32 c2 = stt[C2[g]];
            int4 j0 = S1[(u32)i2.x];  u32 cj0 = stt[C1[i2.x]];
            int4 j1 = S1[(u32)i2.y];  u32 cj1 = stt[C1[i2.y]];
            int4 j2 = S1[(u32)i2.z];  u32 cj2 = stt[C1[i2.z]];
            int4 j3 = S1[(u32)i2.w];  u32 cj3 = stt[C1[i2.w]];

            if (r > 1) wait_done(ws, r - 1, sub, tid, 1);

            const uint4* Sp = (const uint4*)(Sb + (size_t)(2 * r - 2) * WPL);
            // 20 gathers, all issued up-front for ILP.
            uint4 A  = Sp[(u32)i1.x], B  = Sp[(u32)i1.y],
                  C  = Sp[(u32)i1.z], D  = Sp[(u32)i1.w];
            uint4 A0 = Sp[(u32)j0.x], B0 = Sp[(u32)j0.y],
                  C0 = Sp[(u32)j0.z], D0 = Sp[(u32)j0.w];
            uint4 A1 = Sp[(u32)j1.x], B1 = Sp[(u32)j1.y],
                  C1v= Sp[(u32)j1.z], D1 = Sp[(u32)j1.w];
            uint4 A2 = Sp[(u32)j2.x], B2 = Sp[(u32)j2.y],
                  C2v= Sp[(u32)j2.z], D2 = Sp[(u32)j2.w];
            uint4 A3 = Sp[(u32)j3.x], B3 = Sp[(u32)j3.y],
                  C3 = Sp[(u32)j3.z], D3 = Sp[(u32)j3.w];

            u32 m[16];
            // Own odd-layer gate.
            lut_masks(c1, m);
            u32 o0 = lut_mux(m, A.x, B.x, C.x, D.x);
            u32 o1 = lut_mux(m, A.y, B.y, C.y, D.y);
            u32 o2 = lut_mux(m, A.z, B.z, C.z, D.z);
            u32 o3 = lut_mux(m, A.w, B.w, C.w, D.w);
            u64* d1 = (u64*)(Sb + (size_t)l1 * WPL + (size_t)g * 4);
            agent_store64(d1,     ((u64)o1 << 32) | o0);
            agent_store64(d1 + 1, ((u64)o3 << 32) | o2);
            // Transient cone sources (odd layer), then own even-layer gate.
            uint4 s0, s1v, s2v, s3v;
            lut_masks(cj0, m);
            s0.x = lut_mux(m, A0.x,B0.x,C0.x,D0.x); s0.y = lut_mux(m, A0.y,B0.y,C0.y,D0.y);
            s0.z = lut_mux(m, A0.z,B0.z,C0.z,D0.z); s0.w = lut_mux(m, A0.w,B0.w,C0.w,D0.w);
            lut_masks(cj1, m);
            s1v.x = lut_mux(m, A1.x,B1.x,C1v.x,D1.x); s1v.y = lut_mux(m, A1.y,B1.y,C1v.y,D1.y);
            s1v.z = lut_mux(m, A1.z,B1.z,C1v.z,D1.z); s1v.w = lut_mux(m, A1.w,B1.w,C1v.w,D1.w);
            lut_masks(cj2, m);
            s2v.x = lut_mux(m, A2.x,B2.x,C2v.x,D2.x); s2v.y = lut_mux(m, A2.y,B2.y,C2v.y,D2.y);
            s2v.z = lut_mux(m, A2.z,B2.z,C2v.z,D2.z); s2v.w = lut_mux(m, A2.w,B2.w,C2v.w,D2.w);
            lut_masks(cj3, m);
            s3v.x = lut_mux(m, A3.x,B3.x,C3.x,D3.x); s3v.y = lut_mux(m, A3.y,B3.y,C3.y,D3.y);
            s3v.z = lut_mux(m, A3.z,B3.z,C3.z,D3.z); s3v.w = lut_mux(m, A3.w,B3.w,C3.w,D3.w);
            lut_masks(c2, m);
            u32 e0 = lut_mux(m, s0.x, s1v.x, s2v.x, s3v.x);
            u32 e1 = lut_mux(m, s0.y, s1v.y, s2v.y, s3v.y);
            u32 e2 = lut_mux(m, s0.z, s1v.z, s2v.z, s3v.z);
            u32 e3 = lut_mux(m, s0.w, s1v.w, s2v.w, s3v.w);
            u64* d2 = (u64*)(Sb + (size_t)l2 * WPL + (size_t)g * 4);
            agent_store64(d2,     ((u64)e1 << 32) | e0);
            agent_store64(d2 + 1, ((u64)e3 << 32) | e2);

            asm volatile("s_waitcnt vmcnt(0)" ::: "memory");  // stores acked
            __syncthreads();
            if (tid == 0) {
                u32* subp = ws + WS_SUB_OFF + (size_t)r * 1024 + sub * 16;
                u32 old = agent_add(subp, 1u);
                if (old == (u32)(NC / 16 - 1)) {
                    u32 old2 = agent_add(ws + WS_LVL2_OFF + (size_t)r * 16, 1u);
                    if (old2 == 15u) {
                        u32* donep = ws + WS_DONE_OFF + (size_t)r * 1024;
                        #pragma unroll
                        for (int j = 0; j < 64; ++j)   // lines 0..15 first:
                            agent_store(donep + j * 16, 1u);  // compute wakes
                    }
                }
            }
        }
    } else {
        // ---------------- unpack role: woken once per round ----------------
        int ub = blockIdx.x - NC;
        bool sliced = (NU & 7) == 0;
        int x = ub & 7;
        u32 per = (u32)(NU >> 3);
        for (int r = 0; r <= NROUND; ++r) {
            if (r >= 1) wait_done(ws, r, ub & 63, tid, 8);
            int lbeg = (r == 0) ? 0 : 2 * r - 1;
            int lend = (r == 0) ? 0 : 2 * r;
            for (int l = lbeg; l <= lend; ++l) {
                const u32* Sl = Sb + (size_t)l * WPL;
                f4* ob = (f4*)(out + (size_t)l * WGATES * BATCH);
                if (sliced) {
                    u32 sbeg = (u32)x * (F4L / 8), send = sbeg + F4L / 8;
                    for (u32 i = sbeg + (u32)(ub >> 3) * 256u + tid; i < send;
                         i += per * 256u) {
                        u32 wb = Sl[i >> 3];
                        u32 sh = (i & 7) * 4;
                        f4 f;
                        f.x = ((wb >> (sh    )) & 1) ? 1.0f : 0.0f;
                        f.y = ((wb >> (sh + 1)) & 1) ? 1.0f : 0.0f;
                        f.z = ((wb >> (sh + 2)) & 1) ? 1.0f : 0.0f;
                        f.w = ((wb >> (sh + 3)) & 1) ? 1.0f : 0.0f;
                        __builtin_nontemporal_store(f, ob + i);
                    }
                } else {
                    for (u32 i = (u32)ub * 256u + tid; i < (u32)F4L;
                         i += (u32)NU * 256u) {
                        u32 wb = Sl[i >> 3];
                        u32 sh = (i & 7) * 4;
                        f4 f;
                        f.x = ((wb >> (sh    )) & 1) ? 1.0f : 0.0f;
                        f.y = ((wb >> (sh + 1)) & 1) ? 1.0f : 0.0f;
                        f.z = ((wb >> (sh + 2)) & 1) ? 1.0f : 0.0f;
                        f.w = ((wb >> (sh + 3)) & 1) ? 1.0f : 0.0f;
                        __builtin_nontemporal_store(f, ob + i);
                    }
                }
            }
        }
    }
}

// ======================= R2 fallback path (proven) =========================
__global__ void pack_kernel_fb(const float* __restrict__ feature,
                               const float* __restrict__ activation,
                               float* __restrict__ out,
                               u32* __restrict__ tt_ws,
                               u32* __restrict__ buf0) {
    int t = blockIdx.x * 256 + threadIdx.x;
    if (blockIdx.x == 0 && threadIdx.x < NTYPES) {
        u32 tt = 0;
        #pragma unroll
        for (int m = 0; m < 16; ++m)
            tt |= (activation[threadIdx.x * 16 + m] != 0.0f ? 1u : 0u) << m;
        tt_ws[threadIdx.x] = tt;
    }
    float v = feature[t];
    out[t] = v;
    u64 m = __ballot(v != 0.0f);
    if ((t & 63) == 0)
        ((u64*)buf0)[t >> 6] = m;
}

__global__ void fused_kernel_fb(const u32* __restrict__ prev,
                                u32* __restrict__ next,
                                const int* __restrict__ src_idx,
                                const int* __restrict__ cell_type,
                                const u32* __restrict__ tt_ws,
                                const u32* __restrict__ upacked,
                                float* __restrict__ uout,
                                int do_compute)
{
    int tid = threadIdx.x;
    if (do_compute && blockIdx.x < 512) {
        int gl = tid >> 2, q = tid & 3;
        int wg = blockIdx.x * 64 + gl;
        const int4 s = ((const int4*)src_idx)[wg];
        u32 tt = tt_ws[cell_type[wg]];
        u32 m[16];
        lut_masks(tt, m);
        u32 a = prev[(size_t)s.x * 4 + q];
        u32 b = prev[(size_t)s.y * 4 + q];
        u32 c = prev[(size_t)s.z * 4 + q];
        u32 d = prev[(size_t)s.w * 4 + q];
        next[(size_t)wg * 4 + q] = lut_mux(m, a, b, c, d);
        return;
    }
    if (uout == nullptr) return;
    int ub = do_compute ? (int)blockIdx.x - 512 : (int)blockIdx.x;
    #pragma unroll
    for (int r = 0; r < 2; ++r) {
        int fi = ((ub * 2 + r) * 256 + tid) * 4;
        u32 wb = upacked[fi >> 5];
        int sh = fi & 31;
        f4 f;
        f.x = ((wb >> (sh    )) & 1) ? 1.0f : 0.0f;
        f.y = ((wb >> (sh + 1)) & 1) ? 1.0f : 0.0f;
        f.z = ((wb >> (sh + 2)) & 1) ? 1.0f : 0.0f;
        f.w = ((wb >> (sh + 3)) & 1) ? 1.0f : 0.0f;
        ((f4*)uout)[fi >> 2] = f;
    }
}

static void launch_fallback(const float* feature, const float* activation,
                            const int* src_idx, const int* cell_type,
                            float* out, void* d_ws, hipStream_t stream) {
    u32* tt_ws = (u32*)d_ws;
    u32* bufA = (u32*)((char*)d_ws + 1024);
    u32* bufB = (u32*)((char*)d_ws + 1024 + WGATES * 16);
    pack_kernel_fb<<<WGATES * BATCH / 256, 256, 0, stream>>>(
        feature, activation, out, tt_ws, bufA);
    for (int l = 1; l <= LAYERS; ++l) {
        u32* prev = ((l - 1) & 1) ? bufB : bufA;
        u32* next = ((l - 1) & 1) ? bufA : bufB;
        float* uout = (l >= 2) ? out + (size_t)(l - 1) * WGATES * BATCH : nullptr;
        fused_kernel_fb<<<512 + 2048, 256, 0, stream>>>(
            prev, next,
            src_idx + (size_t)(l - 1) * WGATES * 4,
            cell_type + (size_t)(l - 1) * WGATES,
            tt_ws, prev, uout, 1);
    }
    u32* s32 = ((LAYERS - 1) & 1) ? bufA : bufB;
    fused_kernel_fb<<<2048, 256, 0, stream>>>(
        s32, s32, src_idx, cell_type, tt_ws,
        s32, out + (size_t)LAYERS * WGATES * BATCH, 0);
}

extern "C" void kernel_launch(void* const* d_in, const int* in_sizes, int n_in,
                              void* d_out, int out_size, void* d_ws, size_t ws_size,
                              hipStream_t stream) {
    const float* feature    = (const float*)d_in[0];
    const float* activation = (const float*)d_in[1];
    const int*   src_idx    = (const int*)d_in[2];
    const int*   cell_type  = (const int*)d_in[3];
    float* out = (float*)d_out;

    bool coop_ok = (ws_size >= WS_NEED_BYTES);
    int G = 0, NU = 0;
    if (coop_ok) {
        int dev = 0;
        (void)hipGetDevice(&dev);
        int numCU = 0, bpc = 0;
        if (hipDeviceGetAttribute(&numCU, hipDeviceAttributeMultiprocessorCount, dev)
                != hipSuccess) coop_ok = false;
        if (coop_ok &&
            hipOccupancyMaxActiveBlocksPerMultiprocessor(
                &bpc, (const void*)coop_kernel, 256, 0) != hipSuccess) coop_ok = false;
        if (coop_ok) {
            G = bpc * numCU;
            if (G > 2048) G = 2048;
            NU = G - NC;
            if (NU < 256) coop_ok = false;
        }
    }

    if (coop_ok) {
        u32* ws = (u32*)d_ws;
        pack_main<<<WGATES * BATCH / 256, 256, 0, stream>>>(feature, activation, ws);
        void* args[] = {(void*)&src_idx, (void*)&cell_type, (void*)&ws,
                        (void*)&out, (void*)&NU};
        hipError_t e = hipLaunchCooperativeKernel(
            (const void*)coop_kernel, dim3(G), dim3(256), args, 0, stream);
        if (e == hipSuccess) return;
        // cooperative launch rejected -> fall through
    }
    launch_fallback(feature, activation, src_idx, cell_type, out, d_ws, stream);
}

// Round 10
// 235.474 us; speedup vs baseline: 1.0597x; 1.0597x over previous
//
#include <hip/hip_runtime.h>
#include <stdint.h>

typedef uint32_t u32;
typedef unsigned long long u64;
typedef float f4 __attribute__((ext_vector_type(4)));

#define WGATES 32768
#define BATCH  128
#define LAYERS 32
#define NTYPES 16
#define NC 128                          // compute-role blocks (1 gate/thread)
#define WPL (WGATES * 4)                // packed words per layer = 131072
#define F4L (WGATES * BATCH / 4)        // float4 per layer block = 1048576

// ws layout (u32 units):
//   [0,16)              tt truth tables
//   [1024, ...)         sub-counters: layer l at 1024+l*1024, j at +j*16
//   [34816, ...)        lvl2 counters: layer l at 34816+l*16
//   [35840, ...)        done flags: layer l at 35840+l*1024, j=0..63 at +j*16
//   [69632, ...)        packed states:
//     v8 (untagged): 33 * WPL u32
//     epoch (tagged): 33 * WPL u64, word w of layer l at u64[l*WPL+w] =
//                     (tag=l)<<32 | value. Written once per launch; stale
//                     copies from prior replays carry identical values.
#define WS_SUB_OFF    1024
#define WS_LVL2_OFF   34816
#define WS_DONE_OFF   35840
#define WS_S_OFF      69632
#define WS_NEED_V8    ((size_t)(WS_S_OFF + 33 * WPL) * 4)
#define WS_NEED_EP    ((size_t)WS_S_OFF * 4 + (size_t)33 * WPL * 8)

__device__ __forceinline__ u32 agent_load(const u32* p) {
    return __hip_atomic_load(p, __ATOMIC_RELAXED, __HIP_MEMORY_SCOPE_AGENT);
}
__device__ __forceinline__ void agent_store(u32* p, u32 v) {
    __hip_atomic_store(p, v, __ATOMIC_RELAXED, __HIP_MEMORY_SCOPE_AGENT);
}
__device__ __forceinline__ u64 agent_load64(const u64* p) {
    return __hip_atomic_load(p, __ATOMIC_RELAXED, __HIP_MEMORY_SCOPE_AGENT);
}
__device__ __forceinline__ void agent_store64(u64* p, u64 v) {
    __hip_atomic_store(p, v, __ATOMIC_RELAXED, __HIP_MEMORY_SCOPE_AGENT);
}
__device__ __forceinline__ u32 agent_add(u32* p, u32 v) {
    return __hip_atomic_fetch_add(p, v, __ATOMIC_RELAXED, __HIP_MEMORY_SCOPE_AGENT);
}

__device__ __forceinline__ void lut_masks(u32 tt, u32 m[16]) {
    #pragma unroll
    for (int j = 0; j < 16; ++j)
        m[j] = (u32)(((int)(tt << (31 - j))) >> 31);
}
__device__ __forceinline__ u32 lut_mux(const u32 m[16], u32 a, u32 b, u32 c, u32 d) {
    u32 na = ~a, nb = ~b, nc = ~c, nd = ~d;
    u32 v0 = (m[1]&a)|(m[0]&na),  v1 = (m[3]&a)|(m[2]&na);
    u32 v2 = (m[5]&a)|(m[4]&na),  v3 = (m[7]&a)|(m[6]&na);
    u32 v4 = (m[9]&a)|(m[8]&na),  v5 = (m[11]&a)|(m[10]&na);
    u32 v6 = (m[13]&a)|(m[12]&na),v7 = (m[15]&a)|(m[14]&na);
    u32 u0 = (b&v1)|(nb&v0), u1 = (b&v3)|(nb&v2);
    u32 u2 = (b&v5)|(nb&v4), u3 = (b&v7)|(nb&v6);
    u32 w0 = (c&u1)|(nc&u0), w1 = (c&u3)|(nc&u2);
    return (d&w1)|(nd&w0);
}

__device__ __forceinline__ void wait_done(const u32* ws, int l, int line,
                                          int tid, int slp) {
    if (tid == 0) {
        const u32* p = ws + WS_DONE_OFF + (size_t)l * 1024 + line * 16;
        if (slp == 1) { while (agent_load(p) == 0) __builtin_amdgcn_s_sleep(1); }
        else         { while (agent_load(p) == 0) __builtin_amdgcn_s_sleep(8); }
    }
    __syncthreads();
    asm volatile("" ::: "memory");
}

// ---------------------------------------------------------------------------
// pack_main: tt tables -> ws, zero sync state, pack h0 -> S_0 (tagged or not).
// ---------------------------------------------------------------------------
__global__ void pack_main(const float* __restrict__ feature,
                          const float* __restrict__ activation,
                          u32* __restrict__ ws, int tagged) {
    int t = blockIdx.x * 256 + threadIdx.x;
    if (blockIdx.x == 0 && threadIdx.x < NTYPES) {
        u32 tt = 0;
        #pragma unroll
        for (int m = 0; m < 16; ++m)
            tt |= (activation[threadIdx.x * 16 + m] != 0.0f ? 1u : 0u) << m;
        ws[threadIdx.x] = tt;
    }
    int z = (int)blockIdx.x - 1;
    if (z >= 0 && z < 268)             // zero [1024, 69632): sub+lvl2+done
        ws[1024 + z * 256 + threadIdx.x] = 0;
    float v = feature[t];
    u64 m = __ballot(v != 0.0f);
    if ((t & 63) == 0) {
        u32 k = (u32)(t >> 6);         // word pair (2k, 2k+1)
        if (tagged) {
            u64* S0 = (u64*)(ws + WS_S_OFF);
            S0[2 * k]     = (u64)(u32)m;        // tag 0 in hi dword
            S0[2 * k + 1] = (m >> 32);
        } else {
            ((u64*)(ws + WS_S_OFF))[k] = m;
        }
    }
}

// ---------------------------------------------------------------------------
// EPOCH kernel: self-timed dataflow. Packed words carry their layer tag; the
// compute chain has NO global barrier — each gate proceeds when its own 4
// sources pass the tag check (normal load fast path, sc1 retry for stale).
// Arrival tree retained ONLY to wake the unpack role, deferred off-chain.
// ---------------------------------------------------------------------------
#define FIXQ(X, P)                                                          \
    while ((X).y != expt || (X).w != expt) {                                \
        u64 fa = agent_load64(P); u64 fb = agent_load64((P) + 1);           \
        (X).x = (u32)fa; (X).y = (u32)(fa >> 32);                           \
        (X).z = (u32)fb; (X).w = (u32)(fb >> 32);                           \
        if ((X).y == expt && (X).w == expt) break;                          \
        __builtin_amdgcn_s_sleep(1);                                        \
    }

__global__ __launch_bounds__(256) void coop_epoch(
        const int* __restrict__ src_idx,
        const int* __restrict__ cell_type,
        u32* __restrict__ ws,
        float* __restrict__ out,
        int NU)
{
    u64* S64 = (u64*)(ws + WS_S_OFF);
    int tid = threadIdx.x;
    __shared__ u32 stt[NTYPES];
    if (tid < NTYPES) stt[tid] = ws[tid];
    __syncthreads();

    if ((int)blockIdx.x < NC) {
        // -------- compute role: gate-per-thread, tag-synced --------
        int g = blockIdx.x * 256 + tid;
        int sub = blockIdx.x & 15;
        const int4* SI = (const int4*)src_idx;
        int4 idx = SI[g];                       // layer-1 indices
        int ctv = cell_type[g];
        for (int l = 1; l <= LAYERS; ++l) {
            const u64* Sp = S64 + (size_t)(l - 1) * WPL;
            u64* Sn = S64 + (size_t)l * WPL;
            u32 expt = (u32)(l - 1);
            const u64* pa = Sp + (size_t)(u32)idx.x * 4;
            const u64* pb = Sp + (size_t)(u32)idx.y * 4;
            const u64* pc = Sp + (size_t)(u32)idx.z * 4;
            const u64* pd = Sp + (size_t)(u32)idx.w * 4;
            // Issue all 8 gathers up front (normal cached loads).
            uint4 A0 = *(const uint4*)pa, A1 = *(const uint4*)(pa + 2);
            uint4 B0 = *(const uint4*)pb, B1 = *(const uint4*)(pb + 2);
            uint4 C0 = *(const uint4*)pc, C1 = *(const uint4*)(pc + 2);
            uint4 D0 = *(const uint4*)pd, D1 = *(const uint4*)(pd + 2);
            // Prefetch next layer's indices (hides under retry/compute).
            int4 idxn = idx; int ctn = ctv;
            if (l < LAYERS) {
                idxn = SI[(size_t)l * WGATES + g];
                ctn = cell_type[(size_t)l * WGATES + g];
            }
            // Deferred arrival for layer l-1 (off the dependency chain).
            if (l > 1) {
                asm volatile("s_waitcnt vmcnt(0)" ::: "memory");
                __syncthreads();
                if (tid == 0) {
                    u32* subp = ws + WS_SUB_OFF + (size_t)(l - 1) * 1024 + sub * 16;
                    if (agent_add(subp, 1u) == (u32)(NC / 16 - 1)) {
                        if (agent_add(ws + WS_LVL2_OFF + (size_t)(l - 1) * 16, 1u) == 15u) {
                            u32* donep = ws + WS_DONE_OFF + (size_t)(l - 1) * 1024;
                            #pragma unroll
                            for (int j = 0; j < 64; ++j)
                                agent_store(donep + j * 16, 1u);
                        }
                    }
                }
            }
            // Tag check + sc1 retry for stale words.
            FIXQ(A0, pa) FIXQ(A1, pa + 2)
            FIXQ(B0, pb) FIXQ(B1, pb + 2)
            FIXQ(C0, pc) FIXQ(C1, pc + 2)
            FIXQ(D0, pd) FIXQ(D1, pd + 2)
            u32 m[16];
            lut_masks(stt[ctv], m);
            u32 r0 = lut_mux(m, A0.x, B0.x, C0.x, D0.x);
            u32 r1 = lut_mux(m, A0.z, B0.z, C0.z, D0.z);
            u32 r2 = lut_mux(m, A1.x, B1.x, C1.x, D1.x);
            u32 r3 = lut_mux(m, A1.z, B1.z, C1.z, D1.z);
            u64* dst = Sn + (size_t)g * 4;
            u64 tg = (u64)(u32)l << 32;
            agent_store64(dst + 0, tg | r0);   // fire-and-forget sc1
            agent_store64(dst + 1, tg | r1);
            agent_store64(dst + 2, tg | r2);
            agent_store64(dst + 3, tg | r3);
            idx = idxn; ctv = ctn;
        }
        // Final arrival (layer 32) for the unpack role.
        asm volatile("s_waitcnt vmcnt(0)" ::: "memory");
        __syncthreads();
        if (tid == 0) {
            u32* subp = ws + WS_SUB_OFF + (size_t)LAYERS * 1024 + sub * 16;
            if (agent_add(subp, 1u) == (u32)(NC / 16 - 1)) {
                if (agent_add(ws + WS_LVL2_OFF + (size_t)LAYERS * 16, 1u) == 15u) {
                    u32* donep = ws + WS_DONE_OFF + (size_t)LAYERS * 1024;
                    #pragma unroll
                    for (int j = 0; j < 64; ++j)
                        agent_store(donep + j * 16, 1u);
                }
            }
        }
    } else {
        // -------- unpack role: flag-gated, tag-verified reads --------
        int ub = blockIdx.x - NC;
        bool sliced = (NU & 7) == 0;
        int x = ub & 7;
        u32 per = (u32)(NU >> 3);
        for (int l = 0; l <= LAYERS; ++l) {
            if (l >= 1) wait_done(ws, l, ub & 63, tid, 8);
            const u64* Sl = S64 + (size_t)l * WPL;
            u32 expt = (u32)l;
            f4* ob = (f4*)(out + (size_t)l * WGATES * BATCH);
            u32 ibeg, iend, istep;
            if (sliced) {
                ibeg = (u32)x * (F4L / 8) + (u32)(ub >> 3) * 256u + tid;
                iend = (u32)x * (F4L / 8) + F4L / 8;
                istep = per * 256u;
            } else {
                ibeg = (u32)ub * 256u + tid; iend = (u32)F4L; istep = (u32)NU * 256u;
            }
            for (u32 i = ibeg; i < iend; i += istep) {
                u64 v = Sl[i >> 3];            // normal cached load
                if ((u32)(v >> 32) != expt) {  // stale-L2 line: sc1 retry
                    do { v = agent_load64(Sl + (i >> 3)); }
                    while ((u32)(v >> 32) != expt);
                }
                u32 wb = (u32)v;
                u32 sh = (i & 7) * 4;
                f4 f;
                f.x = ((wb >> (sh    )) & 1) ? 1.0f : 0.0f;
                f.y = ((wb >> (sh + 1)) & 1) ? 1.0f : 0.0f;
                f.z = ((wb >> (sh + 2)) & 1) ? 1.0f : 0.0f;
                f.w = ((wb >> (sh + 3)) & 1) ? 1.0f : 0.0f;
                __builtin_nontemporal_store(f, ob + i);
            }
        }
    }
}

// ---------------------------------------------------------------------------
// V8 kernel (proven, 166us): barrier-per-layer producer-consumer. Used when
// ws is too small for the tagged state.
// ---------------------------------------------------------------------------
__global__ __launch_bounds__(256) void coop_v8(
        const int* __restrict__ src_idx,
        const int* __restrict__ cell_type,
        u32* __restrict__ ws,
        float* __restrict__ out,
        int NU)
{
    u32* Sb = ws + WS_S_OFF;
    int tid = threadIdx.x;
    __shared__ u32 stt[NTYPES];
    if (tid < NTYPES) stt[tid] = ws[tid];
    __syncthreads();

    if ((int)blockIdx.x < NC) {
        int g = blockIdx.x * 256 + tid;
        int sub = blockIdx.x & 15;
        for (int l = 1; l <= LAYERS; ++l) {
            const int4 s = ((const int4*)(src_idx + (size_t)(l - 1) * WGATES * 4))[g];
            u32 ttv = stt[cell_type[(size_t)(l - 1) * WGATES + g]];
            if (l > 1) wait_done(ws, l - 1, sub, tid, 1);
            const uint4* Sp = (const uint4*)(Sb + (size_t)(l - 1) * WPL);
            uint4 A = Sp[(u32)s.x];
            uint4 B = Sp[(u32)s.y];
            uint4 C = Sp[(u32)s.z];
            uint4 D = Sp[(u32)s.w];
            u32 m[16];
            lut_masks(ttv, m);
            u32 r0 = lut_mux(m, A.x, B.x, C.x, D.x);
            u32 r1 = lut_mux(m, A.y, B.y, C.y, D.y);
            u32 r2 = lut_mux(m, A.z, B.z, C.z, D.z);
            u32 r3 = lut_mux(m, A.w, B.w, C.w, D.w);
            u64* dst = (u64*)(Sb + (size_t)l * WPL + (size_t)g * 4);
            agent_store64(dst,     ((u64)r1 << 32) | r0);
            agent_store64(dst + 1, ((u64)r3 << 32) | r2);
            asm volatile("s_waitcnt vmcnt(0)" ::: "memory");
            __syncthreads();
            if (tid == 0) {
                u32* subp = ws + WS_SUB_OFF + (size_t)l * 1024 + sub * 16;
                if (agent_add(subp, 1u) == (u32)(NC / 16 - 1)) {
                    if (agent_add(ws + WS_LVL2_OFF + (size_t)l * 16, 1u) == 15u) {
                        u32* donep = ws + WS_DONE_OFF + (size_t)l * 1024;
                        #pragma unroll
                        for (int j = 0; j < 64; ++j)
                            agent_store(donep + j * 16, 1u);
                    }
                }
            }
        }
    } else {
        int ub = blockIdx.x - NC;
        bool sliced = (NU & 7) == 0;
        int x = ub & 7;
        u32 per = (u32)(NU >> 3);
        for (int l = 0; l <= LAYERS; ++l) {
            if (l >= 1) wait_done(ws, l, ub & 63, tid, 8);
            const u32* Sl = Sb + (size_t)l * WPL;
            f4* ob = (f4*)(out + (size_t)l * WGATES * BATCH);
            u32 ibeg, iend, istep;
            if (sliced) {
                ibeg = (u32)x * (F4L / 8) + (u32)(ub >> 3) * 256u + tid;
                iend = (u32)x * (F4L / 8) + F4L / 8;
                istep = per * 256u;
            } else {
                ibeg = (u32)ub * 256u + tid; iend = (u32)F4L; istep = (u32)NU * 256u;
            }
            for (u32 i = ibeg; i < iend; i += istep) {
                u32 wb = Sl[i >> 3];
                u32 sh = (i & 7) * 4;
                f4 f;
                f.x = ((wb >> (sh    )) & 1) ? 1.0f : 0.0f;
                f.y = ((wb >> (sh + 1)) & 1) ? 1.0f : 0.0f;
                f.z = ((wb >> (sh + 2)) & 1) ? 1.0f : 0.0f;
                f.w = ((wb >> (sh + 3)) & 1) ? 1.0f : 0.0f;
                __builtin_nontemporal_store(f, ob + i);
            }
        }
    }
}

// ======================= R2 fallback path (proven) =========================
__global__ void pack_kernel_fb(const float* __restrict__ feature,
                               const float* __restrict__ activation,
                               float* __restrict__ out,
                               u32* __restrict__ tt_ws,
                               u32* __restrict__ buf0) {
    int t = blockIdx.x * 256 + threadIdx.x;
    if (blockIdx.x == 0 && threadIdx.x < NTYPES) {
        u32 tt = 0;
        #pragma unroll
        for (int m = 0; m < 16; ++m)
            tt |= (activation[threadIdx.x * 16 + m] != 0.0f ? 1u : 0u) << m;
        tt_ws[threadIdx.x] = tt;
    }
    float v = feature[t];
    out[t] = v;
    u64 m = __ballot(v != 0.0f);
    if ((t & 63) == 0)
        ((u64*)buf0)[t >> 6] = m;
}

__global__ void fused_kernel_fb(const u32* __restrict__ prev,
                                u32* __restrict__ next,
                                const int* __restrict__ src_idx,
                                const int* __restrict__ cell_type,
                                const u32* __restrict__ tt_ws,
                                const u32* __restrict__ upacked,
                                float* __restrict__ uout,
                                int do_compute)
{
    int tid = threadIdx.x;
    if (do_compute && blockIdx.x < 512) {
        int gl = tid >> 2, q = tid & 3;
        int wg = blockIdx.x * 64 + gl;
        const int4 s = ((const int4*)src_idx)[wg];
        u32 tt = tt_ws[cell_type[wg]];
        u32 m[16];
        lut_masks(tt, m);
        u32 a = prev[(size_t)s.x * 4 + q];
        u32 b = prev[(size_t)s.y * 4 + q];
        u32 c = prev[(size_t)s.z * 4 + q];
        u32 d = prev[(size_t)s.w * 4 + q];
        next[(size_t)wg * 4 + q] = lut_mux(m, a, b, c, d);
        return;
    }
    if (uout == nullptr) return;
    int ub = do_compute ? (int)blockIdx.x - 512 : (int)blockIdx.x;
    #pragma unroll
    for (int r = 0; r < 2; ++r) {
        int fi = ((ub * 2 + r) * 256 + tid) * 4;
        u32 wb = upacked[fi >> 5];
        int sh = fi & 31;
        f4 f;
        f.x = ((wb >> (sh    )) & 1) ? 1.0f : 0.0f;
        f.y = ((wb >> (sh + 1)) & 1) ? 1.0f : 0.0f;
        f.z = ((wb >> (sh + 2)) & 1) ? 1.0f : 0.0f;
        f.w = ((wb >> (sh + 3)) & 1) ? 1.0f : 0.0f;
        ((f4*)uout)[fi >> 2] = f;
    }
}

static void launch_fallback(const float* feature, const float* activation,
                            const int* src_idx, const int* cell_type,
                            float* out, void* d_ws, hipStream_t stream) {
    u32* tt_ws = (u32*)d_ws;
    u32* bufA = (u32*)((char*)d_ws + 1024);
    u32* bufB = (u32*)((char*)d_ws + 1024 + WGATES * 16);
    pack_kernel_fb<<<WGATES * BATCH / 256, 256, 0, stream>>>(
        feature, activation, out, tt_ws, bufA);
    for (int l = 1; l <= LAYERS; ++l) {
        u32* prev = ((l - 1) & 1) ? bufB : bufA;
        u32* next = ((l - 1) & 1) ? bufA : bufB;
        float* uout = (l >= 2) ? out + (size_t)(l - 1) * WGATES * BATCH : nullptr;
        fused_kernel_fb<<<512 + 2048, 256, 0, stream>>>(
            prev, next,
            src_idx + (size_t)(l - 1) * WGATES * 4,
            cell_type + (size_t)(l - 1) * WGATES,
            tt_ws, prev, uout, 1);
    }
    u32* s32 = ((LAYERS - 1) & 1) ? bufA : bufB;
    fused_kernel_fb<<<2048, 256, 0, stream>>>(
        s32, s32, src_idx, cell_type, tt_ws,
        s32, out + (size_t)LAYERS * WGATES * BATCH, 0);
}

extern "C" void kernel_launch(void* const* d_in, const int* in_sizes, int n_in,
                              void* d_out, int out_size, void* d_ws, size_t ws_size,
                              hipStream_t stream) {
    const float* feature    = (const float*)d_in[0];
    const float* activation = (const float*)d_in[1];
    const int*   src_idx    = (const int*)d_in[2];
    const int*   cell_type  = (const int*)d_in[3];
    float* out = (float*)d_out;

    bool use_ep = (ws_size >= WS_NEED_EP);
    bool use_v8 = !use_ep && (ws_size >= WS_NEED_V8);
    int G = 0, NU = 0;
    bool coop_ok = use_ep || use_v8;
    const void* kfn = use_ep ? (const void*)coop_epoch : (const void*)coop_v8;
    if (coop_ok) {
        int dev = 0;
        (void)hipGetDevice(&dev);
        int numCU = 0, bpc = 0;
        if (hipDeviceGetAttribute(&numCU, hipDeviceAttributeMultiprocessorCount, dev)
                != hipSuccess) coop_ok = false;
        if (coop_ok &&
            hipOccupancyMaxActiveBlocksPerMultiprocessor(
                &bpc, kfn, 256, 0) != hipSuccess) coop_ok = false;
        if (coop_ok) {
            G = bpc * numCU;
            if (G > 2048) G = 2048;
            NU = G - NC;
            if (NU < 256) coop_ok = false;
        }
    }

    if (coop_ok) {
        u32* ws = (u32*)d_ws;
        int tagged = use_ep ? 1 : 0;
        pack_main<<<WGATES * BATCH / 256, 256, 0, stream>>>(
            feature, activation, ws, tagged);
        void* args[] = {(void*)&src_idx, (void*)&cell_type, (void*)&ws,
                        (void*)&out, (void*)&NU};
        hipError_t e = hipLaunchCooperativeKernel(
            kfn, dim3(G), dim3(256), args, 0, stream);
        if (e == hipSuccess) return;
        // cooperative launch rejected -> fall through
    }
    launch_fallback(feature, activation, src_idx, cell_type, out, d_ws, stream);
}

// Round 11
// 216.562 us; speedup vs baseline: 1.1522x; 1.0873x over previous
//
#include <hip/hip_runtime.h>
#include <stdint.h>

typedef uint32_t u32;
typedef unsigned long long u64;
typedef float f4 __attribute__((ext_vector_type(4)));

#define WGATES 32768
#define BATCH  128
#define LAYERS 32
#define NTYPES 16
#define NC 128                          // compute-role blocks (1 gate/thread)
#define WPL (WGATES * 4)                // packed words per layer = 131072
#define F4L (WGATES * BATCH / 4)        // float4 per layer block = 1048576

// ws layout (u32 units):
//   [0,16)              tt truth tables
//   [1024, ...)         sub-counters: layer l at 1024+l*1024, j=0..15 at +j*16
//   [34816, ...)        lvl2 counters: layer l at 34816+l*16 (target 16)
//   [35840, ...)        done flags: layer l at 35840+l*1024, j=0..63 at +j*16
//   [69632, +33*WPL)    packed states S_0..S_32 (each address written once)
#define WS_SUB_OFF    1024
#define WS_LVL2_OFF   34816
#define WS_DONE_OFF   35840
#define WS_S_OFF      69632
#define WS_NEED_BYTES ((size_t)(WS_S_OFF + 33 * WPL) * 4)

// Agent-scope (sc1) accesses: ONLY for sync + state release. Data reads use
// normal cached loads (each S_l address is written once per launch; consumers
// first-touch only after the producer's sc1 store reached the coherence pt).
__device__ __forceinline__ u32 agent_load(const u32* p) {
    return __hip_atomic_load(p, __ATOMIC_RELAXED, __HIP_MEMORY_SCOPE_AGENT);
}
__device__ __forceinline__ void agent_store(u32* p, u32 v) {
    __hip_atomic_store(p, v, __ATOMIC_RELAXED, __HIP_MEMORY_SCOPE_AGENT);
}
__device__ __forceinline__ void agent_store64(u64* p, u64 v) {
    __hip_atomic_store(p, v, __ATOMIC_RELAXED, __HIP_MEMORY_SCOPE_AGENT);
}
__device__ __forceinline__ u32 agent_add(u32* p, u32 v) {
    return __hip_atomic_fetch_add(p, v, __ATOMIC_RELAXED, __HIP_MEMORY_SCOPE_AGENT);
}

__device__ __forceinline__ void lut_masks(u32 tt, u32 m[16]) {
    #pragma unroll
    for (int j = 0; j < 16; ++j)
        m[j] = (u32)(((int)(tt << (31 - j))) >> 31);
}
__device__ __forceinline__ u32 lut_mux(const u32 m[16], u32 a, u32 b, u32 c, u32 d) {
    u32 na = ~a, nb = ~b, nc = ~c, nd = ~d;
    u32 v0 = (m[1]&a)|(m[0]&na),  v1 = (m[3]&a)|(m[2]&na);
    u32 v2 = (m[5]&a)|(m[4]&na),  v3 = (m[7]&a)|(m[6]&na);
    u32 v4 = (m[9]&a)|(m[8]&na),  v5 = (m[11]&a)|(m[10]&na);
    u32 v6 = (m[13]&a)|(m[12]&na),v7 = (m[15]&a)|(m[14]&na);
    u32 u0 = (b&v1)|(nb&v0), u1 = (b&v3)|(nb&v2);
    u32 u2 = (b&v5)|(nb&v4), u3 = (b&v7)|(nb&v6);
    u32 w0 = (c&u1)|(nc&u0), w1 = (c&u3)|(nc&u2);
    return (d&w1)|(nd&w0);
}

// Unpack-role wait: poll a spread done line.
__device__ __forceinline__ void wait_done(const u32* ws, int l, int line, int tid) {
    if (tid == 0) {
        const u32* p = ws + WS_DONE_OFF + (size_t)l * 1024 + line * 16;
        while (agent_load(p) == 0) __builtin_amdgcn_s_sleep(8);
    }
    __syncthreads();
    asm volatile("" ::: "memory");
}

// Compute-role wait: poll the lvl2 counter directly (skips the bcast leg).
__device__ __forceinline__ void wait_lvl2(const u32* ws, int l, int tid) {
    if (tid == 0) {
        const u32* p = ws + WS_LVL2_OFF + (size_t)l * 16;
        while (agent_load(p) < 16u) __builtin_amdgcn_s_sleep(1);
    }
    __syncthreads();
    asm volatile("" ::: "memory");
}

// ---------------------------------------------------------------------------
// pack_main: tt tables -> ws, zero all sync state, pack h0 -> S_0.
// ---------------------------------------------------------------------------
__global__ void pack_main(const float* __restrict__ feature,
                          const float* __restrict__ activation,
                          u32* __restrict__ ws) {
    int t = blockIdx.x * 256 + threadIdx.x;
    if (blockIdx.x == 0 && threadIdx.x < NTYPES) {
        u32 tt = 0;
        #pragma unroll
        for (int m = 0; m < 16; ++m)
            tt |= (activation[threadIdx.x * 16 + m] != 0.0f ? 1u : 0u) << m;
        ws[threadIdx.x] = tt;
    }
    int z = (int)blockIdx.x - 1;
    if (z >= 0 && z < 268)             // zero [1024, 69632): sub+lvl2+done
        ws[1024 + z * 256 + threadIdx.x] = 0;
    float v = feature[t];
    u64 m = __ballot(v != 0.0f);
    if ((t & 63) == 0)
        ((u64*)(ws + WS_S_OFF))[t >> 6] = m;
}

// ---------------------------------------------------------------------------
// Persistent producer-consumer kernel (cooperative launch for residency).
// Blocks [0,NC): compute chain S_1..S_32, tree arrival; wait on lvl2 direct.
// Blocks [NC,NC+NU): stream-unpack S_0..S_32, gated by done-bcast, with a
// short post-flag stagger so compute's next-layer gathers see a quiet fabric.
// ---------------------------------------------------------------------------
__global__ __launch_bounds__(256) void coop_kernel(
        const int* __restrict__ src_idx,
        const int* __restrict__ cell_type,
        u32* __restrict__ ws,
        float* __restrict__ out,
        int NU)
{
    u32* Sb = ws + WS_S_OFF;
    int tid = threadIdx.x;
    __shared__ u32 stt[NTYPES];
    if (tid < NTYPES) stt[tid] = ws[tid];
    __syncthreads();

    if ((int)blockIdx.x < NC) {
        // ---------------- compute role: gate-per-thread ----------------
        int g = blockIdx.x * 256 + tid;     // gate id in [0, WGATES)
        int sub = blockIdx.x & 15;          // 16 sub-counters x 8 blocks
        for (int l = 1; l <= LAYERS; ++l) {
            // Index loads issued BEFORE the gate: latency hides under wait.
            const int4 s = ((const int4*)(src_idx + (size_t)(l - 1) * WGATES * 4))[g];
            u32 ttv = stt[cell_type[(size_t)(l - 1) * WGATES + g]];
            if (l > 1) wait_lvl2(ws, l - 1, tid);
            const uint4* Sp = (const uint4*)(Sb + (size_t)(l - 1) * WPL);
            uint4 A = Sp[(u32)s.x];          // normal cached dwordx4 loads
            uint4 B = Sp[(u32)s.y];
            uint4 C = Sp[(u32)s.z];
            uint4 D = Sp[(u32)s.w];
            u32 m[16];
            lut_masks(ttv, m);
            u32 r0 = lut_mux(m, A.x, B.x, C.x, D.x);
            u32 r1 = lut_mux(m, A.y, B.y, C.y, D.y);
            u32 r2 = lut_mux(m, A.z, B.z, C.z, D.z);
            u32 r3 = lut_mux(m, A.w, B.w, C.w, D.w);
            u64* dst = (u64*)(Sb + (size_t)l * WPL + (size_t)g * 4);
            agent_store64(dst,     ((u64)r1 << 32) | r0);   // sc1 release
            agent_store64(dst + 1, ((u64)r3 << 32) | r2);
            asm volatile("s_waitcnt vmcnt(0)" ::: "memory");  // stores acked
            __syncthreads();
            if (tid == 0) {
                u32* subp = ws + WS_SUB_OFF + (size_t)l * 1024 + sub * 16;
                if (agent_add(subp, 1u) == (u32)(NC / 16 - 1)) {
                    if (agent_add(ws + WS_LVL2_OFF + (size_t)l * 16, 1u) == 15u) {
                        // lvl2 just reached 16: compute waiters see it now.
                        // Bcast done lines for the unpack waiters only.
                        u32* donep = ws + WS_DONE_OFF + (size_t)l * 1024;
                        #pragma unroll
                        for (int j = 0; j < 64; ++j)
                            agent_store(donep + j * 16, 1u);
                    }
                }
            }
        }
    } else {
        // ---------------- unpack role ----------------
        int ub = blockIdx.x - NC;
        bool sliced = (NU & 7) == 0;        // XCD-affine slicing
        int x = ub & 7;
        u32 per = (u32)(NU >> 3);
        for (int l = 0; l <= LAYERS; ++l) {
            if (l >= 1) {
                wait_done(ws, l, ub & 63, tid);
                // Stagger ~0.6us: let compute's layer-l+1 gathers through
                // before this role's write burst saturates the fabric.
                __builtin_amdgcn_s_sleep(24);
            }
            const u32* Sl = Sb + (size_t)l * WPL;
            f4* ob = (f4*)(out + (size_t)l * WGATES * BATCH);
            u32 ibeg, iend, istep;
            if (sliced) {
                ibeg = (u32)x * (F4L / 8) + (u32)(ub >> 3) * 256u + tid;
                iend = (u32)x * (F4L / 8) + F4L / 8;
                istep = per * 256u;
            } else {
                ibeg = (u32)ub * 256u + tid; iend = (u32)F4L; istep = (u32)NU * 256u;
            }
            for (u32 i = ibeg; i < iend; i += istep) {
                u32 wb = Sl[i >> 3];               // cached (L2/L3-resident)
                u32 sh = (i & 7) * 4;
                f4 f;
                f.x = ((wb >> (sh    )) & 1) ? 1.0f : 0.0f;
                f.y = ((wb >> (sh + 1)) & 1) ? 1.0f : 0.0f;
                f.z = ((wb >> (sh + 2)) & 1) ? 1.0f : 0.0f;
                f.w = ((wb >> (sh + 3)) & 1) ? 1.0f : 0.0f;
                __builtin_nontemporal_store(f, ob + i);   // out never re-read
            }
        }
    }
}

// ======================= R2 fallback path (proven) =========================
__global__ void pack_kernel_fb(const float* __restrict__ feature,
                               const float* __restrict__ activation,
                               float* __restrict__ out,
                               u32* __restrict__ tt_ws,
                               u32* __restrict__ buf0) {
    int t = blockIdx.x * 256 + threadIdx.x;
    if (blockIdx.x == 0 && threadIdx.x < NTYPES) {
        u32 tt = 0;
        #pragma unroll
        for (int m = 0; m < 16; ++m)
            tt |= (activation[threadIdx.x * 16 + m] != 0.0f ? 1u : 0u) << m;
        tt_ws[threadIdx.x] = tt;
    }
    float v = feature[t];
    out[t] = v;
    u64 m = __ballot(v != 0.0f);
    if ((t & 63) == 0)
        ((u64*)buf0)[t >> 6] = m;
}

__global__ void fused_kernel_fb(const u32* __restrict__ prev,
                                u32* __restrict__ next,
                                const int* __restrict__ src_idx,
                                const int* __restrict__ cell_type,
                                const u32* __restrict__ tt_ws,
                                const u32* __restrict__ upacked,
                                float* __restrict__ uout,
                                int do_compute)
{
    int tid = threadIdx.x;
    if (do_compute && blockIdx.x < 512) {
        int gl = tid >> 2, q = tid & 3;
        int wg = blockIdx.x * 64 + gl;
        const int4 s = ((const int4*)src_idx)[wg];
        u32 tt = tt_ws[cell_type[wg]];
        u32 m[16];
        lut_masks(tt, m);
        u32 a = prev[(size_t)s.x * 4 + q];
        u32 b = prev[(size_t)s.y * 4 + q];
        u32 c = prev[(size_t)s.z * 4 + q];
        u32 d = prev[(size_t)s.w * 4 + q];
        next[(size_t)wg * 4 + q] = lut_mux(m, a, b, c, d);
        return;
    }
    if (uout == nullptr) return;
    int ub = do_compute ? (int)blockIdx.x - 512 : (int)blockIdx.x;
    #pragma unroll
    for (int r = 0; r < 2; ++r) {
        int fi = ((ub * 2 + r) * 256 + tid) * 4;
        u32 wb = upacked[fi >> 5];
        int sh = fi & 31;
        f4 f;
        f.x = ((wb >> (sh    )) & 1) ? 1.0f : 0.0f;
        f.y = ((wb >> (sh + 1)) & 1) ? 1.0f : 0.0f;
        f.z = ((wb >> (sh + 2)) & 1) ? 1.0f : 0.0f;
        f.w = ((wb >> (sh + 3)) & 1) ? 1.0f : 0.0f;
        ((f4*)uout)[fi >> 2] = f;
    }
}

static void launch_fallback(const float* feature, const float* activation,
                            const int* src_idx, const int* cell_type,
                            float* out, void* d_ws, hipStream_t stream) {
    u32* tt_ws = (u32*)d_ws;
    u32* bufA = (u32*)((char*)d_ws + 1024);
    u32* bufB = (u32*)((char*)d_ws + 1024 + WGATES * 16);
    pack_kernel_fb<<<WGATES * BATCH / 256, 256, 0, stream>>>(
        feature, activation, out, tt_ws, bufA);
    for (int l = 1; l <= LAYERS; ++l) {
        u32* prev = ((l - 1) & 1) ? bufB : bufA;
        u32* next = ((l - 1) & 1) ? bufA : bufB;
        float* uout = (l >= 2) ? out + (size_t)(l - 1) * WGATES * BATCH : nullptr;
        fused_kernel_fb<<<512 + 2048, 256, 0, stream>>>(
            prev, next,
            src_idx + (size_t)(l - 1) * WGATES * 4,
            cell_type + (size_t)(l - 1) * WGATES,
            tt_ws, prev, uout, 1);
    }
    u32* s32 = ((LAYERS - 1) & 1) ? bufA : bufB;
    fused_kernel_fb<<<2048, 256, 0, stream>>>(
        s32, s32, src_idx, cell_type, tt_ws,
        s32, out + (size_t)LAYERS * WGATES * BATCH, 0);
}

extern "C" void kernel_launch(void* const* d_in, const int* in_sizes, int n_in,
                              void* d_out, int out_size, void* d_ws, size_t ws_size,
                              hipStream_t stream) {
    const float* feature    = (const float*)d_in[0];
    const float* activation = (const float*)d_in[1];
    const int*   src_idx    = (const int*)d_in[2];
    const int*   cell_type  = (const int*)d_in[3];
    float* out = (float*)d_out;

    bool coop_ok = (ws_size >= WS_NEED_BYTES);
    int G = 0, NU = 0;
    if (coop_ok) {
        int dev = 0;
        (void)hipGetDevice(&dev);
        int numCU = 0, bpc = 0;
        if (hipDeviceGetAttribute(&numCU, hipDeviceAttributeMultiprocessorCount, dev)
                != hipSuccess) coop_ok = false;
        if (coop_ok &&
            hipOccupancyMaxActiveBlocksPerMultiprocessor(
                &bpc, (const void*)coop_kernel, 256, 0) != hipSuccess) coop_ok = false;
        if (coop_ok) {
            G = bpc * numCU;
            if (G > 2048) G = 2048;
            NU = G - NC;
            if (NU < 256) coop_ok = false;
        }
    }

    if (coop_ok) {
        u32* ws = (u32*)d_ws;
        pack_main<<<WGATES * BATCH / 256, 256, 0, stream>>>(feature, activation, ws);
        void* args[] = {(void*)&src_idx, (void*)&cell_type, (void*)&ws,
                        (void*)&out, (void*)&NU};
        hipError_t e = hipLaunchCooperativeKernel(
            (const void*)coop_kernel, dim3(G), dim3(256), args, 0, stream);
        if (e == hipSuccess) return;
        // cooperative launch rejected -> fall through
    }
    launch_fallback(feature, activation, src_idx, cell_type, out, d_ws, stream);
}

// Round 12
// 174.448 us; speedup vs baseline: 1.4304x; 1.2414x over previous
//
#include <hip/hip_runtime.h>
#include <stdint.h>

typedef uint32_t u32;
typedef unsigned long long u64;
typedef float f4 __attribute__((ext_vector_type(4)));

#define WGATES 32768
#define BATCH  128
#define LAYERS 32
#define NTYPES 16
#define NCB 512                         // symmetric blocks, 1 word/thread
#define WPL (WGATES * 4)                // packed words per layer = 131072
#define F4L (WGATES * BATCH / 4)

// ws layout (u32 units):
//   [0,16)              tt truth tables
//   [1024, ...)         sub-counters: layer l at 1024+l*1024, j=0..31 at +j*16
//   [34816, ...)        lvl2 counters: layer l at 34816+l*16 (target 32)
//   [35840, ...)        done flags: layer l at 35840+l*1024, j=0..63 at +j*16
//   [69632, +33*WPL)    packed states S_0..S_32 (each address written once)
#define WS_SUB_OFF    1024
#define WS_LVL2_OFF   34816
#define WS_DONE_OFF   35840
#define WS_S_OFF      69632
#define WS_NEED_BYTES ((size_t)(WS_S_OFF + 33 * WPL) * 4)

__device__ __forceinline__ u32 agent_load(const u32* p) {
    return __hip_atomic_load(p, __ATOMIC_RELAXED, __HIP_MEMORY_SCOPE_AGENT);
}
__device__ __forceinline__ void agent_store(u32* p, u32 v) {
    __hip_atomic_store(p, v, __ATOMIC_RELAXED, __HIP_MEMORY_SCOPE_AGENT);
}
__device__ __forceinline__ void agent_store64(u64* p, u64 v) {
    __hip_atomic_store(p, v, __ATOMIC_RELAXED, __HIP_MEMORY_SCOPE_AGENT);
}
__device__ __forceinline__ u32 agent_add(u32* p, u32 v) {
    return __hip_atomic_fetch_add(p, v, __ATOMIC_RELAXED, __HIP_MEMORY_SCOPE_AGENT);
}

__device__ __forceinline__ void lut_masks(u32 tt, u32 m[16]) {
    #pragma unroll
    for (int j = 0; j < 16; ++j)
        m[j] = (u32)(((int)(tt << (31 - j))) >> 31);
}
__device__ __forceinline__ u32 lut_mux(const u32 m[16], u32 a, u32 b, u32 c, u32 d) {
    u32 na = ~a, nb = ~b, nc = ~c, nd = ~d;
    u32 v0 = (m[1]&a)|(m[0]&na),  v1 = (m[3]&a)|(m[2]&na);
    u32 v2 = (m[5]&a)|(m[4]&na),  v3 = (m[7]&a)|(m[6]&na);
    u32 v4 = (m[9]&a)|(m[8]&na),  v5 = (m[11]&a)|(m[10]&na);
    u32 v6 = (m[13]&a)|(m[12]&na),v7 = (m[15]&a)|(m[14]&na);
    u32 u0 = (b&v1)|(nb&v0), u1 = (b&v3)|(nb&v2);
    u32 u2 = (b&v5)|(nb&v4), u3 = (b&v7)|(nb&v6);
    u32 w0 = (c&u1)|(nc&u0), w1 = (c&u3)|(nc&u2);
    return (d&w1)|(nd&w0);
}

// Spread-line poll: 8 pollers/line at sleep(1) (R8-proven density).
__device__ __forceinline__ void wait_done(const u32* ws, int l, int line, int tid) {
    if (tid == 0) {
        const u32* p = ws + WS_DONE_OFF + (size_t)l * 1024 + line * 16;
        while (agent_load(p) == 0) __builtin_amdgcn_s_sleep(1);
    }
    __syncthreads();
    asm volatile("" ::: "memory");
}

// ---------------------------------------------------------------------------
// pack_main: tt tables -> ws, zero all sync state, pack h0 -> S_0.
// ---------------------------------------------------------------------------
__global__ void pack_main(const float* __restrict__ feature,
                          const float* __restrict__ activation,
                          u32* __restrict__ ws) {
    int t = blockIdx.x * 256 + threadIdx.x;
    if (blockIdx.x == 0 && threadIdx.x < NTYPES) {
        u32 tt = 0;
        #pragma unroll
        for (int m = 0; m < 16; ++m)
            tt |= (activation[threadIdx.x * 16 + m] != 0.0f ? 1u : 0u) << m;
        ws[threadIdx.x] = tt;
    }
    int z = (int)blockIdx.x - 1;
    if (z >= 0 && z < 268)             // zero [1024, 69632): sub+lvl2+done
        ws[1024 + z * 256 + threadIdx.x] = 0;
    float v = feature[t];
    u64 m = __ballot(v != 0.0f);
    if ((t & 63) == 0)
        ((u64*)(ws + WS_S_OFF))[t >> 6] = m;
}

// ---------------------------------------------------------------------------
// Symmetric persistent kernel: 512 blocks, word-per-thread.
// Per layer: wait(l-1) -> 4 scalar gathers -> LUT -> LDS pack -> 128 sc1 u64
// stores -> ack -> tree arrive -> unpack OWN 64 gates from LDS to floats
// (fills the sync-leg dead time; zero state re-reads) -> loop.
// ---------------------------------------------------------------------------
__global__ __launch_bounds__(256) void coop_sym(
        const int* __restrict__ src_idx,
        const int* __restrict__ cell_type,
        u32* __restrict__ ws,
        float* __restrict__ out)
{
    __shared__ u32 stt[NTYPES];
    __shared__ u32 lp[256];             // block's 256 packed words (64 gates)
    int tid = threadIdx.x;
    if (tid < NTYPES) stt[tid] = ws[tid];
    u32* Sb = ws + WS_S_OFF;
    int w0 = blockIdx.x * 256;          // first word id of this block
    int g  = (w0 + tid) >> 2;           // gate of this thread
    int q  = tid & 3;                   // batch word within gate
    int sub   = blockIdx.x & 31;        // 32 sub-counters x 16 arrivals
    int dline = blockIdx.x & 63;        // 64 done lines x 8 pollers
    __syncthreads();

    // ---- S_0 floats (no wait needed: pack_main completed at launch) ----
    {
        lp[tid] = Sb[w0 + tid];
        __syncthreads();
        f4* ob = (f4*)out + (size_t)blockIdx.x * 2048;
        #pragma unroll
        for (int j = 0; j < 8; ++j) {
            int fi = j * 1024 + tid * 4;
            u32 wb = lp[fi >> 5];
            int sh = fi & 31;
            f4 f;
            f.x = ((wb >> (sh    )) & 1) ? 1.0f : 0.0f;
            f.y = ((wb >> (sh + 1)) & 1) ? 1.0f : 0.0f;
            f.z = ((wb >> (sh + 2)) & 1) ? 1.0f : 0.0f;
            f.w = ((wb >> (sh + 3)) & 1) ? 1.0f : 0.0f;
            __builtin_nontemporal_store(f, ob + (fi >> 2));
        }
        __syncthreads();
    }

    for (int l = 1; l <= LAYERS; ++l) {
        // Index loads issued BEFORE the gate (latency hides under the wait).
        const int4 s = ((const int4*)(src_idx + (size_t)(l - 1) * WGATES * 4))[g];
        u32 ttv = stt[cell_type[(size_t)(l - 1) * WGATES + g]];
        if (l > 1) wait_done(ws, l - 1, dline, tid);
        const u32* Sp = Sb + (size_t)(l - 1) * WPL;
        u32 a = Sp[(u32)s.x * 4 + q];   // normal cached loads (first touch
        u32 b = Sp[(u32)s.y * 4 + q];   //  misses to the coherence point)
        u32 c = Sp[(u32)s.z * 4 + q];
        u32 d = Sp[(u32)s.w * 4 + q];
        u32 m[16];
        lut_masks(ttv, m);
        u32 r = lut_mux(m, a, b, c, d);
        lp[tid] = r;
        __syncthreads();
        if (tid < 128) {                // coalesced sc1 release, 8B grain
            u64 v = ((u64)lp[2 * tid + 1] << 32) | lp[2 * tid];
            agent_store64((u64*)(Sb + (size_t)l * WPL) +
                          (size_t)blockIdx.x * 128 + tid, v);
        }
        asm volatile("s_waitcnt vmcnt(0)" ::: "memory");  // stores acked
        __syncthreads();
        if (tid == 0) {
            u32* subp = ws + WS_SUB_OFF + (size_t)l * 1024 + sub * 16;
            if (agent_add(subp, 1u) == 15u) {              // 16 per sub
                if (agent_add(ws + WS_LVL2_OFF + (size_t)l * 16, 1u) == 31u) {
                    u32* donep = ws + WS_DONE_OFF + (size_t)l * 1024;
                    #pragma unroll
                    for (int j = 0; j < 64; ++j)
                        agent_store(donep + j * 16, 1u);
                }
            }
        }
        // Unpack own 64 gates from LDS -> floats; fills sync dead time.
        f4* ob = (f4*)(out + (size_t)l * WGATES * BATCH) +
                 (size_t)blockIdx.x * 2048;
        #pragma unroll
        for (int j = 0; j < 8; ++j) {
            int fi = j * 1024 + tid * 4;
            u32 wb = lp[fi >> 5];
            int sh = fi & 31;
            f4 f;
            f.x = ((wb >> (sh    )) & 1) ? 1.0f : 0.0f;
            f.y = ((wb >> (sh + 1)) & 1) ? 1.0f : 0.0f;
            f.z = ((wb >> (sh + 2)) & 1) ? 1.0f : 0.0f;
            f.w = ((wb >> (sh + 3)) & 1) ? 1.0f : 0.0f;
            __builtin_nontemporal_store(f, ob + (fi >> 2));
        }
        // lp reuse is safe: next overwrite happens after wait_done(l)'s
        // __syncthreads (all threads have finished their lp reads above).
    }
}

// ======================= R2 fallback path (proven) =========================
__global__ void pack_kernel_fb(const float* __restrict__ feature,
                               const float* __restrict__ activation,
                               float* __restrict__ out,
                               u32* __restrict__ tt_ws,
                               u32* __restrict__ buf0) {
    int t = blockIdx.x * 256 + threadIdx.x;
    if (blockIdx.x == 0 && threadIdx.x < NTYPES) {
        u32 tt = 0;
        #pragma unroll
        for (int m = 0; m < 16; ++m)
            tt |= (activation[threadIdx.x * 16 + m] != 0.0f ? 1u : 0u) << m;
        tt_ws[threadIdx.x] = tt;
    }
    float v = feature[t];
    out[t] = v;
    u64 m = __ballot(v != 0.0f);
    if ((t & 63) == 0)
        ((u64*)buf0)[t >> 6] = m;
}

__global__ void fused_kernel_fb(const u32* __restrict__ prev,
                                u32* __restrict__ next,
                                const int* __restrict__ src_idx,
                                const int* __restrict__ cell_type,
                                const u32* __restrict__ tt_ws,
                                const u32* __restrict__ upacked,
                                float* __restrict__ uout,
                                int do_compute)
{
    int tid = threadIdx.x;
    if (do_compute && blockIdx.x < 512) {
        int gl = tid >> 2, q = tid & 3;
        int wg = blockIdx.x * 64 + gl;
        const int4 s = ((const int4*)src_idx)[wg];
        u32 tt = tt_ws[cell_type[wg]];
        u32 m[16];
        lut_masks(tt, m);
        u32 a = prev[(size_t)s.x * 4 + q];
        u32 b = prev[(size_t)s.y * 4 + q];
        u32 c = prev[(size_t)s.z * 4 + q];
        u32 d = prev[(size_t)s.w * 4 + q];
        next[(size_t)wg * 4 + q] = lut_mux(m, a, b, c, d);
        return;
    }
    if (uout == nullptr) return;
    int ub = do_compute ? (int)blockIdx.x - 512 : (int)blockIdx.x;
    #pragma unroll
    for (int r = 0; r < 2; ++r) {
        int fi = ((ub * 2 + r) * 256 + tid) * 4;
        u32 wb = upacked[fi >> 5];
        int sh = fi & 31;
        f4 f;
        f.x = ((wb >> (sh    )) & 1) ? 1.0f : 0.0f;
        f.y = ((wb >> (sh + 1)) & 1) ? 1.0f : 0.0f;
        f.z = ((wb >> (sh + 2)) & 1) ? 1.0f : 0.0f;
        f.w = ((wb >> (sh + 3)) & 1) ? 1.0f : 0.0f;
        ((f4*)uout)[fi >> 2] = f;
    }
}

static void launch_fallback(const float* feature, const float* activation,
                            const int* src_idx, const int* cell_type,
                            float* out, void* d_ws, hipStream_t stream) {
    u32* tt_ws = (u32*)d_ws;
    u32* bufA = (u32*)((char*)d_ws + 1024);
    u32* bufB = (u32*)((char*)d_ws + 1024 + WGATES * 16);
    pack_kernel_fb<<<WGATES * BATCH / 256, 256, 0, stream>>>(
        feature, activation, out, tt_ws, bufA);
    for (int l = 1; l <= LAYERS; ++l) {
        u32* prev = ((l - 1) & 1) ? bufB : bufA;
        u32* next = ((l - 1) & 1) ? bufA : bufB;
        float* uout = (l >= 2) ? out + (size_t)(l - 1) * WGATES * BATCH : nullptr;
        fused_kernel_fb<<<512 + 2048, 256, 0, stream>>>(
            prev, next,
            src_idx + (size_t)(l - 1) * WGATES * 4,
            cell_type + (size_t)(l - 1) * WGATES,
            tt_ws, prev, uout, 1);
    }
    u32* s32 = ((LAYERS - 1) & 1) ? bufA : bufB;
    fused_kernel_fb<<<2048, 256, 0, stream>>>(
        s32, s32, src_idx, cell_type, tt_ws,
        s32, out + (size_t)LAYERS * WGATES * BATCH, 0);
}

extern "C" void kernel_launch(void* const* d_in, const int* in_sizes, int n_in,
                              void* d_out, int out_size, void* d_ws, size_t ws_size,
                              hipStream_t stream) {
    const float* feature    = (const float*)d_in[0];
    const float* activation = (const float*)d_in[1];
    const int*   src_idx    = (const int*)d_in[2];
    const int*   cell_type  = (const int*)d_in[3];
    float* out = (float*)d_out;

    bool coop_ok = (ws_size >= WS_NEED_BYTES);
    if (coop_ok) {
        int dev = 0;
        (void)hipGetDevice(&dev);
        int numCU = 0, bpc = 0;
        if (hipDeviceGetAttribute(&numCU, hipDeviceAttributeMultiprocessorCount, dev)
                != hipSuccess) coop_ok = false;
        if (coop_ok &&
            hipOccupancyMaxActiveBlocksPerMultiprocessor(
                &bpc, (const void*)coop_sym, 256, 0) != hipSuccess) coop_ok = false;
        if (coop_ok && bpc * numCU < NCB) coop_ok = false;   // must co-reside
    }

    if (coop_ok) {
        u32* ws = (u32*)d_ws;
        pack_main<<<WGATES * BATCH / 256, 256, 0, stream>>>(feature, activation, ws);
        void* args[] = {(void*)&src_idx, (void*)&cell_type, (void*)&ws, (void*)&out};
        hipError_t e = hipLaunchCooperativeKernel(
            (const void*)coop_sym, dim3(NCB), dim3(256), args, 0, stream);
        if (e == hipSuccess) return;
        // cooperative launch rejected -> fall through
    }
    launch_fallback(feature, activation, src_idx, cell_type, out, d_ws, stream);
}

// Round 13
// 165.507 us; speedup vs baseline: 1.5076x; 1.0540x over previous
//
#include <hip/hip_runtime.h>
#include <stdint.h>

typedef uint32_t u32;
typedef unsigned long long u64;
typedef float f4 __attribute__((ext_vector_type(4)));

#define WGATES 32768
#define BATCH  128
#define LAYERS 32
#define NTYPES 16
#define NC 128                          // compute-role blocks (1 gate/thread)
#define WPL (WGATES * 4)                // packed words per layer = 131072
#define F4L (WGATES * BATCH / 4)        // float4 per layer block = 1048576

// ws layout (u32 units):
//   [0,16)              tt truth tables
//   [1024, ...)         sub-counters: layer l at 1024+l*1024, j at +j*16
//   [34816, ...)        lvl2 counters: layer l at 34816+l*16
//   [35840, ...)        done flags: layer l at 35840+l*1024, j=0..63 at +j*16
//   [69632, +33*WPL)    packed states S_0..S_32 (each address written once)
#define WS_SUB_OFF    1024
#define WS_LVL2_OFF   34816
#define WS_DONE_OFF   35840
#define WS_S_OFF      69632
#define WS_NEED_BYTES ((size_t)(WS_S_OFF + 33 * WPL) * 4)

// Agent-scope (sc1) accesses: ONLY for sync + state release. Data reads use
// normal cached loads (each S_l address is written once per launch; consumers
// first-touch only after the producer's sc1 store reached the coherence pt,
// and the kernel-launch acquire invalidated stale lines).
__device__ __forceinline__ u32 agent_load(const u32* p) {
    return __hip_atomic_load(p, __ATOMIC_RELAXED, __HIP_MEMORY_SCOPE_AGENT);
}
__device__ __forceinline__ void agent_store(u32* p, u32 v) {
    __hip_atomic_store(p, v, __ATOMIC_RELAXED, __HIP_MEMORY_SCOPE_AGENT);
}
__device__ __forceinline__ void agent_store64(u64* p, u64 v) {
    __hip_atomic_store(p, v, __ATOMIC_RELAXED, __HIP_MEMORY_SCOPE_AGENT);
}
__device__ __forceinline__ u32 agent_add(u32* p, u32 v) {
    return __hip_atomic_fetch_add(p, v, __ATOMIC_RELAXED, __HIP_MEMORY_SCOPE_AGENT);
}

__device__ __forceinline__ void lut_masks(u32 tt, u32 m[16]) {
    #pragma unroll
    for (int j = 0; j < 16; ++j)
        m[j] = (u32)(((int)(tt << (31 - j))) >> 31);
}
__device__ __forceinline__ u32 lut_mux(const u32 m[16], u32 a, u32 b, u32 c, u32 d) {
    u32 na = ~a, nb = ~b, nc = ~c, nd = ~d;
    u32 v0 = (m[1]&a)|(m[0]&na),  v1 = (m[3]&a)|(m[2]&na);
    u32 v2 = (m[5]&a)|(m[4]&na),  v3 = (m[7]&a)|(m[6]&na);
    u32 v4 = (m[9]&a)|(m[8]&na),  v5 = (m[11]&a)|(m[10]&na);
    u32 v6 = (m[13]&a)|(m[12]&na),v7 = (m[15]&a)|(m[14]&na);
    u32 u0 = (b&v1)|(nb&v0), u1 = (b&v3)|(nb&v2);
    u32 u2 = (b&v5)|(nb&v4), u3 = (b&v7)|(nb&v6);
    u32 w0 = (c&u1)|(nc&u0), w1 = (c&u3)|(nc&u2);
    return (d&w1)|(nd&w0);
}

// Single-lane, single-line poll. Compute role: slp=1 (fast detect, few
// pollers); unpack role: slp=8 (off critical path).
__device__ __forceinline__ void wait_done(const u32* ws, int l, int line,
                                          int tid, int slp) {
    if (tid == 0) {
        const u32* p = ws + WS_DONE_OFF + (size_t)l * 1024 + line * 16;
        if (slp == 1) { while (agent_load(p) == 0) __builtin_amdgcn_s_sleep(1); }
        else         { while (agent_load(p) == 0) __builtin_amdgcn_s_sleep(8); }
    }
    __syncthreads();
    asm volatile("" ::: "memory");   // nothing hoisted above the gate
}

// ---------------------------------------------------------------------------
// pack_main: tt tables -> ws, zero all sync state, pack h0 -> S_0.
// ---------------------------------------------------------------------------
__global__ void pack_main(const float* __restrict__ feature,
                          const float* __restrict__ activation,
                          u32* __restrict__ ws) {
    int t = blockIdx.x * 256 + threadIdx.x;
    if (blockIdx.x == 0 && threadIdx.x < NTYPES) {
        u32 tt = 0;
        #pragma unroll
        for (int m = 0; m < 16; ++m)
            tt |= (activation[threadIdx.x * 16 + m] != 0.0f ? 1u : 0u) << m;
        ws[threadIdx.x] = tt;
    }
    int z = (int)blockIdx.x - 1;
    if (z >= 0 && z < 268)             // zero [1024, 69632): sub+lvl2+done
        ws[1024 + z * 256 + threadIdx.x] = 0;
    float v = feature[t];
    u64 m = __ballot(v != 0.0f);
    if ((t & 63) == 0)
        ((u64*)(ws + WS_S_OFF))[t >> 6] = m;
}

// ---------------------------------------------------------------------------
// Persistent producer-consumer kernel (R8 structure, proven 166us).
// Blocks [0,NC): compute chain, gate-per-thread, setprio(1) to win issue
//   arbitration against co-resident unpack waves.
// Blocks [NC,NC+NU): stream-unpack; post-flag stagger (~0.4us) keeps the
//   fabric quiet while next-layer gathers + sync RMWs fly.
// ---------------------------------------------------------------------------
__global__ __launch_bounds__(256) void coop_kernel(
        const int* __restrict__ src_idx,
        const int* __restrict__ cell_type,
        u32* __restrict__ ws,
        float* __restrict__ out,
        int NU)
{
    u32* Sb = ws + WS_S_OFF;
    int tid = threadIdx.x;
    __shared__ u32 stt[NTYPES];
    if (tid < NTYPES) stt[tid] = ws[tid];
    __syncthreads();

    if ((int)blockIdx.x < NC) {
        // ---------------- compute role: gate-per-thread ----------------
        __builtin_amdgcn_s_setprio(1);      // latency path beats BW path
        int g = blockIdx.x * 256 + tid;     // gate id in [0, WGATES)
        int sub = blockIdx.x & 15;          // 16 sub-counters x 8 blocks
        for (int l = 1; l <= LAYERS; ++l) {
            // Index loads issued BEFORE the gate: latency hides under wait.
            const int4 s = ((const int4*)(src_idx + (size_t)(l - 1) * WGATES * 4))[g];
            u32 ttv = stt[cell_type[(size_t)(l - 1) * WGATES + g]];
            if (l > 1) wait_done(ws, l - 1, sub, tid, 1);
            const uint4* Sp = (const uint4*)(Sb + (size_t)(l - 1) * WPL);
            uint4 A = Sp[(u32)s.x];          // normal cached dwordx4 loads
            uint4 B = Sp[(u32)s.y];
            uint4 C = Sp[(u32)s.z];
            uint4 D = Sp[(u32)s.w];
            u32 m[16];
            lut_masks(ttv, m);
            u32 r0 = lut_mux(m, A.x, B.x, C.x, D.x);
            u32 r1 = lut_mux(m, A.y, B.y, C.y, D.y);
            u32 r2 = lut_mux(m, A.z, B.z, C.z, D.z);
            u32 r3 = lut_mux(m, A.w, B.w, C.w, D.w);
            u64* dst = (u64*)(Sb + (size_t)l * WPL + (size_t)g * 4);
            agent_store64(dst,     ((u64)r1 << 32) | r0);   // sc1 release
            agent_store64(dst + 1, ((u64)r3 << 32) | r2);
            asm volatile("s_waitcnt vmcnt(0)" ::: "memory");  // stores acked
            __syncthreads();
            if (tid == 0) {
                u32* subp = ws + WS_SUB_OFF + (size_t)l * 1024 + sub * 16;
                if (agent_add(subp, 1u) == (u32)(NC / 16 - 1)) {
                    if (agent_add(ws + WS_LVL2_OFF + (size_t)l * 16, 1u) == 15u) {
                        u32* donep = ws + WS_DONE_OFF + (size_t)l * 1024;
                        #pragma unroll
                        for (int j = 0; j < 64; ++j)
                            agent_store(donep + j * 16, 1u);
                    }
                }
            }
        }
    } else {
        // ---------------- unpack role ----------------
        int ub = blockIdx.x - NC;
        bool sliced = (NU & 7) == 0;        // XCD-affine slicing
        int x = ub & 7;
        u32 per = (u32)(NU >> 3);
        for (int l = 0; l <= LAYERS; ++l) {
            if (l >= 1) {
                wait_done(ws, l, ub & 63, tid, 8);
                // Stagger ~0.4us: quiet window for compute's layer-l+1
                // gathers and the sync RMWs before this write burst.
                __builtin_amdgcn_s_sleep(16);
            }
            const u32* Sl = Sb + (size_t)l * WPL;
            f4* ob = (f4*)(out + (size_t)l * WGATES * BATCH);
            u32 ibeg, iend, istep;
            if (sliced) {
                ibeg = (u32)x * (F4L / 8) + (u32)(ub >> 3) * 256u + tid;
                iend = (u32)x * (F4L / 8) + F4L / 8;
                istep = per * 256u;
            } else {
                ibeg = (u32)ub * 256u + tid; iend = (u32)F4L; istep = (u32)NU * 256u;
            }
            for (u32 i = ibeg; i < iend; i += istep) {
                u32 wb = Sl[i >> 3];               // cached (L2/L3-resident)
                u32 sh = (i & 7) * 4;
                f4 f;
                f.x = ((wb >> (sh    )) & 1) ? 1.0f : 0.0f;
                f.y = ((wb >> (sh + 1)) & 1) ? 1.0f : 0.0f;
                f.z = ((wb >> (sh + 2)) & 1) ? 1.0f : 0.0f;
                f.w = ((wb >> (sh + 3)) & 1) ? 1.0f : 0.0f;
                __builtin_nontemporal_store(f, ob + i);   // out never re-read
            }
        }
    }
}

// ======================= R2 fallback path (proven) =========================
__global__ void pack_kernel_fb(const float* __restrict__ feature,
                               const float* __restrict__ activation,
                               float* __restrict__ out,
                               u32* __restrict__ tt_ws,
                               u32* __restrict__ buf0) {
    int t = blockIdx.x * 256 + threadIdx.x;
    if (blockIdx.x == 0 && threadIdx.x < NTYPES) {
        u32 tt = 0;
        #pragma unroll
        for (int m = 0; m < 16; ++m)
            tt |= (activation[threadIdx.x * 16 + m] != 0.0f ? 1u : 0u) << m;
        tt_ws[threadIdx.x] = tt;
    }
    float v = feature[t];
    out[t] = v;
    u64 m = __ballot(v != 0.0f);
    if ((t & 63) == 0)
        ((u64*)buf0)[t >> 6] = m;
}

__global__ void fused_kernel_fb(const u32* __restrict__ prev,
                                u32* __restrict__ next,
                                const int* __restrict__ src_idx,
                                const int* __restrict__ cell_type,
                                const u32* __restrict__ tt_ws,
                                const u32* __restrict__ upacked,
                                float* __restrict__ uout,
                                int do_compute)
{
    int tid = threadIdx.x;
    if (do_compute && blockIdx.x < 512) {
        int gl = tid >> 2, q = tid & 3;
        int wg = blockIdx.x * 64 + gl;
        const int4 s = ((const int4*)src_idx)[wg];
        u32 tt = tt_ws[cell_type[wg]];
        u32 m[16];
        lut_masks(tt, m);
        u32 a = prev[(size_t)s.x * 4 + q];
        u32 b = prev[(size_t)s.y * 4 + q];
        u32 c = prev[(size_t)s.z * 4 + q];
        u32 d = prev[(size_t)s.w * 4 + q];
        next[(size_t)wg * 4 + q] = lut_mux(m, a, b, c, d);
        return;
    }
    if (uout == nullptr) return;
    int ub = do_compute ? (int)blockIdx.x - 512 : (int)blockIdx.x;
    #pragma unroll
    for (int r = 0; r < 2; ++r) {
        int fi = ((ub * 2 + r) * 256 + tid) * 4;
        u32 wb = upacked[fi >> 5];
        int sh = fi & 31;
        f4 f;
        f.x = ((wb >> (sh    )) & 1) ? 1.0f : 0.0f;
        f.y = ((wb >> (sh + 1)) & 1) ? 1.0f : 0.0f;
        f.z = ((wb >> (sh + 2)) & 1) ? 1.0f : 0.0f;
        f.w = ((wb >> (sh + 3)) & 1) ? 1.0f : 0.0f;
        ((f4*)uout)[fi >> 2] = f;
    }
}

static void launch_fallback(const float* feature, const float* activation,
                            const int* src_idx, const int* cell_type,
                            float* out, void* d_ws, hipStream_t stream) {
    u32* tt_ws = (u32*)d_ws;
    u32* bufA = (u32*)((char*)d_ws + 1024);
    u32* bufB = (u32*)((char*)d_ws + 1024 + WGATES * 16);
    pack_kernel_fb<<<WGATES * BATCH / 256, 256, 0, stream>>>(
        feature, activation, out, tt_ws, bufA);
    for (int l = 1; l <= LAYERS; ++l) {
        u32* prev = ((l - 1) & 1) ? bufB : bufA;
        u32* next = ((l - 1) & 1) ? bufA : bufB;
        float* uout = (l >= 2) ? out + (size_t)(l - 1) * WGATES * BATCH : nullptr;
        fused_kernel_fb<<<512 + 2048, 256, 0, stream>>>(
            prev, next,
            src_idx + (size_t)(l - 1) * WGATES * 4,
            cell_type + (size_t)(l - 1) * WGATES,
            tt_ws, prev, uout, 1);
    }
    u32* s32 = ((LAYERS - 1) & 1) ? bufA : bufB;
    fused_kernel_fb<<<2048, 256, 0, stream>>>(
        s32, s32, src_idx, cell_type, tt_ws,
        s32, out + (size_t)LAYERS * WGATES * BATCH, 0);
}

extern "C" void kernel_launch(void* const* d_in, const int* in_sizes, int n_in,
                              void* d_out, int out_size, void* d_ws, size_t ws_size,
                              hipStream_t stream) {
    const float* feature    = (const float*)d_in[0];
    const float* activation = (const float*)d_in[1];
    const int*   src_idx    = (const int*)d_in[2];
    const int*   cell_type  = (const int*)d_in[3];
    float* out = (float*)d_out;

    bool coop_ok = (ws_size >= WS_NEED_BYTES);
    int G = 0, NU = 0;
    if (coop_ok) {
        int dev = 0;
        (void)hipGetDevice(&dev);
        int numCU = 0, bpc = 0;
        if (hipDeviceGetAttribute(&numCU, hipDeviceAttributeMultiprocessorCount, dev)
                != hipSuccess) coop_ok = false;
        if (coop_ok &&
            hipOccupancyMaxActiveBlocksPerMultiprocessor(
                &bpc, (const void*)coop_kernel, 256, 0) != hipSuccess) coop_ok = false;
        if (coop_ok) {
            G = bpc * numCU;
            if (G > 2048) G = 2048;
            NU = G - NC;
            if (NU < 256) coop_ok = false;
        }
    }

    if (coop_ok) {
        u32* ws = (u32*)d_ws;
        pack_main<<<WGATES * BATCH / 256, 256, 0, stream>>>(feature, activation, ws);
        void* args[] = {(void*)&src_idx, (void*)&cell_type, (void*)&ws,
                        (void*)&out, (void*)&NU};
        hipError_t e = hipLaunchCooperativeKernel(
            (const void*)coop_kernel, dim3(G), dim3(256), args, 0, stream);
        if (e == hipSuccess) return;
        // cooperative launch rejected -> fall through
    }
    launch_fallback(feature, activation, src_idx, cell_type, out, d_ws, stream);
}